// Round 1
// baseline (473.507 us; speedup 1.0000x reference)
//
#include <hip/hip_runtime.h>

// EuclideanCodebook: fused dist-GEMM + argmax + gather.
// x: [BT=65536, C=128] fp32, embed: [K=1024, C=128] fp32.
// out = [ quantized (BT*C floats) | embed_ind (BT floats, index values) ]
//
// Compute-bound fp32 (no fp32 MFMA on CDNA4): register-blocked SGEMM,
// argmax fused per 64-code chunk, codebook gather in epilogue.

#define C       128
#define BM      64      // rows per block
#define CH      64      // codes per chunk
#define THREADS 256

// ---------------- e_sq pre-pass: one wave per code ----------------
__global__ __launch_bounds__(256) void esq_kernel(const float* __restrict__ embed,
                                                  float* __restrict__ esq, int K) {
    int gid  = blockIdx.x * blockDim.x + threadIdx.x;
    int code = gid >> 6;
    int lane = threadIdx.x & 63;
    if (code >= K) return;
    float2 v = ((const float2*)(embed + (size_t)code * C))[lane];
    float  s = fmaf(v.x, v.x, v.y * v.y);
    #pragma unroll
    for (int m = 32; m >= 1; m >>= 1) s += __shfl_xor(s, m, 64);
    if (lane == 0) esq[code] = s;
}

// swizzle: permute 16B granules within a 512B row by XOR with ((row>>2)&15)<<4.
// Applied on BOTH the ds_write (staging) and the ds_read (compute) sides.
__device__ __forceinline__ int swz(int row) { return ((row >> 2) & 15) << 4; }

__global__ __launch_bounds__(THREADS) void vq_kernel(
    const float* __restrict__ x, const float* __restrict__ embed,
    const float* __restrict__ esq, float* __restrict__ outq,
    float* __restrict__ outi, int M, int K) {

    __shared__ __align__(16) float xs[BM * C];       // 32KB, swizzled rows
    __shared__ __align__(16) float es[CH * C];       // 32KB, swizzled rows
    __shared__ __align__(16) float esq_lds[1024];
    __shared__ float xsq_part[4][BM];
    __shared__ float xsq[BM];
    __shared__ float red_s[16][BM];
    __shared__ int   red_i[16][BM];
    __shared__ int   winners[BM];

    const int tid  = threadIdx.x;
    const int tx   = tid & 15;          // code-tile coordinate
    const int ty   = tid >> 4;          // row-tile coordinate
    const int lane = tid & 63;
    const int w    = tid >> 6;          // wave id in block
    const int row0 = blockIdx.x * BM;

    // ---- stage x tile (once), swizzled; load e_sq to LDS ----
    {
        const char* xsrc = (const char*)(x + (size_t)row0 * C);
        float4 stg[8];
        #pragma unroll
        for (int i = 0; i < 8; ++i) {
            int L = i * 4096 + w * 1024 + lane * 16;
            stg[i] = *(const float4*)(xsrc + L);
        }
        #pragma unroll
        for (int i = 0; i < 8; ++i) {
            int L = i * 4096 + w * 1024 + lane * 16;
            int r = L >> 9, o = L & 511;
            *(float4*)((char*)xs + (r << 9) + (o ^ swz(r))) = stg[i];
        }
        ((float4*)esq_lds)[tid] = ((const float4*)esq)[tid];
    }
    __syncthreads();

    // ---- x_sq per row: 4 partial segments per row, sequential-k within segment ----
    {
        int r = tid & 63, q = tid >> 6;
        float s = 0.f;
        #pragma unroll
        for (int t = 0; t < 8; ++t) {
            int kb = ((q * 8 + t) << 4);
            float4 v = *(const float4*)((const char*)xs + (r << 9) + (kb ^ swz(r)));
            s = fmaf(v.x, v.x, s); s = fmaf(v.y, v.y, s);
            s = fmaf(v.z, v.z, s); s = fmaf(v.w, v.w, s);
        }
        xsq_part[q][r] = s;
    }
    __syncthreads();
    if (tid < BM)
        xsq[tid] = ((xsq_part[0][tid] + xsq_part[1][tid]) + xsq_part[2][tid]) + xsq_part[3][tid];
    __syncthreads();

    float best[4]; int bidx[4];
    #pragma unroll
    for (int i = 0; i < 4; ++i) { best[i] = -3.402823466e+38f; bidx[i] = 0; }

    const int txs = tx << 4;
    const int tys = ty << 4;
    const char* ap = (const char*)xs + ty * 4 * 512;
    const char* bp = (const char*)es + tx * 4 * 512;

    const int nch = K / CH;   // 16
    for (int ch = 0; ch < nch; ++ch) {
        // issue global loads early (overlap with other waves' compute + barrier)
        float4 stg[8];
        const char* esrc = (const char*)(embed + (size_t)ch * CH * C);
        #pragma unroll
        for (int i = 0; i < 8; ++i) {
            int L = i * 4096 + w * 1024 + lane * 16;
            stg[i] = *(const float4*)(esrc + L);
        }
        __syncthreads();   // all waves done READING es of previous chunk
        #pragma unroll
        for (int i = 0; i < 8; ++i) {
            int L = i * 4096 + w * 1024 + lane * 16;
            int c = L >> 9, o = L & 511;
            *(float4*)((char*)es + (c << 9) + (o ^ swz(c))) = stg[i];
        }
        __syncthreads();   // staged

        float acc[4][4];
        #pragma unroll
        for (int i = 0; i < 4; ++i)
            #pragma unroll
            for (int j = 0; j < 4; ++j) acc[i][j] = 0.f;

        #pragma unroll
        for (int kk = 0; kk < 32; ++kk) {
            const int ao = (kk << 4) ^ tys;   // per-thread-constant XOR swizzle
            const int bo = (kk << 4) ^ txs;
            float4 A[4], B[4];
            #pragma unroll
            for (int i = 0; i < 4; ++i) A[i] = *(const float4*)(ap + i * 512 + ao);
            #pragma unroll
            for (int j = 0; j < 4; ++j) B[j] = *(const float4*)(bp + j * 512 + bo);
            #pragma unroll
            for (int i = 0; i < 4; ++i)
                #pragma unroll
                for (int j = 0; j < 4; ++j) {
                    acc[i][j] = fmaf(A[i].x, B[j].x, acc[i][j]);
                    acc[i][j] = fmaf(A[i].y, B[j].y, acc[i][j]);
                    acc[i][j] = fmaf(A[i].z, B[j].z, acc[i][j]);
                    acc[i][j] = fmaf(A[i].w, B[j].w, acc[i][j]);
                }
        }

        // fused scoring: dist = (2*dot - x_sq) - e_sq ; first-max wins (strict >)
        const int cbase = ch * CH + tx * 4;
        float eq[4];
        #pragma unroll
        for (int j = 0; j < 4; ++j) eq[j] = esq_lds[cbase + j];
        #pragma unroll
        for (int i = 0; i < 4; ++i) {
            float xq = xsq[ty * 4 + i];
            #pragma unroll
            for (int j = 0; j < 4; ++j) {
                float s = fmaf(2.0f, acc[i][j], -xq) - eq[j];
                if (s > best[i]) { best[i] = s; bidx[i] = cbase + j; }
            }
        }
    }

    // ---- cross-thread argmax reduction (16 code-threads per row) ----
    #pragma unroll
    for (int i = 0; i < 4; ++i) {
        red_s[tx][ty * 4 + i] = best[i];
        red_i[tx][ty * 4 + i] = bidx[i];
    }
    __syncthreads();
    if (tid < BM) {
        float bs = red_s[0][tid]; int bi = red_i[0][tid];
        #pragma unroll
        for (int t = 1; t < 16; ++t) {
            float v = red_s[t][tid]; int vi = red_i[t][tid];
            if (v > bs || (v == bs && vi < bi)) { bs = v; bi = vi; }
        }
        winners[tid] = bi;
        outi[row0 + tid] = (float)bi;   // index output stored as fp32 value
    }
    __syncthreads();

    // ---- gather quantized = embed[winner] ----
    #pragma unroll
    for (int i = 0; i < 8; ++i) {
        int pos = i * 256 + tid;          // float4 position within 64x128 tile
        int r = pos >> 5, c4 = pos & 31;
        int idx = winners[r];
        float4 v = ((const float4*)(embed + (size_t)idx * C))[c4];
        ((float4*)(outq + (size_t)(row0 + r) * C))[c4] = v;
    }
}

extern "C" void kernel_launch(void* const* d_in, const int* in_sizes, int n_in,
                              void* d_out, int out_size, void* d_ws, size_t ws_size,
                              hipStream_t stream) {
    const float* x     = (const float*)d_in[0];
    const float* embed = (const float*)d_in[1];
    const int M = in_sizes[0] / C;   // 65536
    const int K = in_sizes[1] / C;   // 1024
    float* outq = (float*)d_out;
    float* outi = outq + (size_t)M * C;
    float* esq  = (float*)d_ws;

    esq_kernel<<<K / 4, 256, 0, stream>>>(embed, esq, K);
    vq_kernel<<<M / BM, THREADS, 0, stream>>>(x, embed, esq, outq, outi, M, K);
}

// Round 2
// 87.138 us; speedup vs baseline: 5.4340x; 5.4340x over previous
//
#include <hip/hip_runtime.h>

// EuclideanCodebook via f16-split MFMA: dot_f32(x,e) ~= xh*eh + xh*el + xl*eh
// (3 MFMA passes, fp32 accumulate; residual < 2^-22 rel => argmax-safe).
// x: [M=65536, C=128] fp32, embed: [K=1024, C=128] fp32.
// out = [ quantized (M*C floats) | embed_ind (M floats) ]

#define C       128
#define BM      64      // rows per block
#define CH      64      // codes per chunk
#define NCH     16
#define THREADS 256

typedef _Float16 f16;
typedef __attribute__((ext_vector_type(4))) _Float16 f16x4;
typedef __attribute__((ext_vector_type(8))) _Float16 f16x8;
typedef __attribute__((ext_vector_type(4))) float    f32x4;

// ---------------- e_sq pre-pass (exact fp32) ----------------
__global__ __launch_bounds__(256) void esq_kernel(const float* __restrict__ embed,
                                                  float* __restrict__ esq, int K) {
    int gid  = blockIdx.x * blockDim.x + threadIdx.x;
    int code = gid >> 6;
    int lane = threadIdx.x & 63;
    if (code >= K) return;
    float2 v = ((const float2*)(embed + (size_t)code * C))[lane];
    float  s = fmaf(v.x, v.x, v.y * v.y);
    #pragma unroll
    for (int m = 32; m >= 1; m >>= 1) s += __shfl_xor(s, m, 64);
    if (lane == 0) esq[code] = s;
}

// XOR-swizzle within a 256B row of f16[128]: spreads rows over bank granules.
__device__ __forceinline__ int swz(int row) { return (row & 7) << 4; }

// convert float4 -> f16 hi + f16 residual, write 8B each (swizzled)
__device__ __forceinline__ void stage_tile(f16* dstH, f16* dstL,
                                           const float4* regs, int tid) {
    #pragma unroll
    for (int i = 0; i < 8; ++i) {
        int pos = i * 256 + tid;
        int r   = pos >> 5;        // row (0..63)
        int c4  = pos & 31;        // float4 index within row
        float4 v = regs[i];
        f16x4 h, lo;
        h[0] = (f16)v.x; lo[0] = (f16)(v.x - (float)h[0]);
        h[1] = (f16)v.y; lo[1] = (f16)(v.y - (float)h[1]);
        h[2] = (f16)v.z; lo[2] = (f16)(v.z - (float)h[2]);
        h[3] = (f16)v.w; lo[3] = (f16)(v.w - (float)h[3]);
        int off = r * 256 + ((c4 * 8) ^ swz(r));
        *(f16x4*)((char*)dstH + off) = h;
        *(f16x4*)((char*)dstL + off) = lo;
    }
}

__global__ __launch_bounds__(THREADS) void vq_mfma_kernel(
    const float* __restrict__ x, const float* __restrict__ embed,
    const float* __restrict__ esq, float* __restrict__ outq,
    float* __restrict__ outi, int M, int K) {

    __shared__ __align__(16) f16 Ah[BM * C];   // 16KB each
    __shared__ __align__(16) f16 Al[BM * C];
    __shared__ __align__(16) f16 Bh[CH * C];
    __shared__ __align__(16) f16 Bl[CH * C];
    __shared__ __align__(16) float esq_lds[1024];
    __shared__ float xsq_part[4][BM];
    __shared__ float xsq_s[BM];
    __shared__ int   winners[BM];

    const int tid  = threadIdx.x;
    const int wid  = tid >> 6;       // wave: owns rows wid*16 .. wid*16+15
    const int l    = tid & 63;
    const int lr   = l & 15;
    const int lg   = l >> 4;
    const int row0 = blockIdx.x * BM;

    const float4* xg = (const float4*)(x + (size_t)row0 * C);
    const float4* eg = (const float4*)embed;

    // ---- prologue: stage A (once) + B chunk 0, esq, xsq ----
    float4 areg[8], breg[8];
    #pragma unroll
    for (int i = 0; i < 8; ++i) areg[i] = xg[i * 256 + tid];
    #pragma unroll
    for (int i = 0; i < 8; ++i) breg[i] = eg[i * 256 + tid];
    ((float4*)esq_lds)[tid] = ((const float4*)esq)[tid];

    stage_tile(Ah, Al, areg, tid);
    stage_tile(Bh, Bl, breg, tid);

    {   // x_sq: 4 sequential-k partial segments per row (exact fp32, fixed order)
        int r = tid & 63, q = tid >> 6;
        const float4* xr = (const float4*)(x + (size_t)(row0 + r) * C);
        float s = 0.f;
        #pragma unroll
        for (int t = 0; t < 8; ++t) {
            float4 v = xr[q * 8 + t];
            s = fmaf(v.x, v.x, s); s = fmaf(v.y, v.y, s);
            s = fmaf(v.z, v.z, s); s = fmaf(v.w, v.w, s);
        }
        xsq_part[q][r] = s;
    }
    __syncthreads();
    if (tid < BM)
        xsq_s[tid] = ((xsq_part[0][tid] + xsq_part[1][tid]) + xsq_part[2][tid]) + xsq_part[3][tid];
    __syncthreads();

    float xsqr[4];
    #pragma unroll
    for (int r = 0; r < 4; ++r) xsqr[r] = xsq_s[wid * 16 + lg * 4 + r];

    float best[4]; int bidx[4];
    #pragma unroll
    for (int r = 0; r < 4; ++r) { best[r] = -3.402823466e+38f; bidx[r] = 0; }

    const int arow = wid * 16 + lr;
    const int abase = arow * 256;
    const int aswz  = swz(arow);

    for (int ch = 0; ch < NCH; ++ch) {
        if (ch + 1 < NCH) {   // issue next chunk's loads early (hide under MFMA)
            #pragma unroll
            for (int i = 0; i < 8; ++i)
                breg[i] = eg[(ch + 1) * 2048 + i * 256 + tid];
        }

        f32x4 acc[4];
        #pragma unroll
        for (int n = 0; n < 4; ++n) acc[n] = (f32x4){0.f, 0.f, 0.f, 0.f};

        #pragma unroll
        for (int kk = 0; kk < 4; ++kk) {
            const int ko = kk * 64 + lg * 16;     // byte offset of k-slice
            f16x8 ah = *(const f16x8*)((const char*)Ah + abase + (ko ^ aswz));
            f16x8 al = *(const f16x8*)((const char*)Al + abase + (ko ^ aswz));
            #pragma unroll
            for (int n = 0; n < 4; ++n) {
                const int brow = n * 16 + lr;
                const int boff = brow * 256 + (ko ^ swz(brow));
                f16x8 bh = *(const f16x8*)((const char*)Bh + boff);
                f16x8 bl = *(const f16x8*)((const char*)Bl + boff);
                acc[n] = __builtin_amdgcn_mfma_f32_16x16x32_f16(ah, bh, acc[n], 0, 0, 0);
                acc[n] = __builtin_amdgcn_mfma_f32_16x16x32_f16(ah, bl, acc[n], 0, 0, 0);
                acc[n] = __builtin_amdgcn_mfma_f32_16x16x32_f16(al, bh, acc[n], 0, 0, 0);
            }
        }

        // fused scoring: dist = (2*dot - x_sq) - e_sq ; first-max wins
        #pragma unroll
        for (int n = 0; n < 4; ++n) {
            const int code = ch * CH + n * 16 + lr;
            const float eq = esq_lds[code];
            #pragma unroll
            for (int r = 0; r < 4; ++r) {
                float s = fmaf(2.0f, acc[n][r], -xsqr[r]) - eq;
                if (s > best[r]) { best[r] = s; bidx[r] = code; }
            }
        }

        if (ch + 1 < NCH) {
            __syncthreads();                     // all waves done reading Bh/Bl
            stage_tile(Bh, Bl, breg, tid);
            __syncthreads();
        }
    }

    // ---- cross-lane argmax (16 lanes share each row group), tie -> lower idx ----
    #pragma unroll
    for (int r = 0; r < 4; ++r) {
        float bs = best[r]; int bi = bidx[r];
        #pragma unroll
        for (int m = 1; m <= 8; m <<= 1) {
            float vs = __shfl_xor(bs, m, 64);
            int   vi = __shfl_xor(bi, m, 64);
            if (vs > bs || (vs == bs && vi < bi)) { bs = vs; bi = vi; }
        }
        if (lr == 0) {
            int row = wid * 16 + lg * 4 + r;
            winners[row] = bi;
            outi[row0 + row] = (float)bi;
        }
    }
    __syncthreads();

    // ---- gather quantized = embed[winner] (exact fp32 copy) ----
    #pragma unroll
    for (int i = 0; i < 8; ++i) {
        int pos = i * 256 + tid;
        int r = pos >> 5, c4 = pos & 31;
        int idx = winners[r];
        float4 v = ((const float4*)(embed + (size_t)idx * C))[c4];
        ((float4*)(outq + (size_t)(row0 + r) * C))[c4] = v;
    }
}

extern "C" void kernel_launch(void* const* d_in, const int* in_sizes, int n_in,
                              void* d_out, int out_size, void* d_ws, size_t ws_size,
                              hipStream_t stream) {
    const float* x     = (const float*)d_in[0];
    const float* embed = (const float*)d_in[1];
    const int M = in_sizes[0] / C;   // 65536
    const int K = in_sizes[1] / C;   // 1024
    float* outq = (float*)d_out;
    float* outi = outq + (size_t)M * C;
    float* esq  = (float*)d_ws;

    esq_kernel<<<K / 4, 256, 0, stream>>>(embed, esq, K);
    vq_mfma_kernel<<<M / BM, THREADS, 0, stream>>>(x, embed, esq, outq, outi, M, K);
}

// Round 3
// 80.160 us; speedup vs baseline: 5.9070x; 1.0870x over previous
//
#include <hip/hip_runtime.h>
#include <float.h>

// EuclideanCodebook, round 3: 32x32x16 f16-split MFMA, A(x) resident in regs,
// B(codebook) pre-converted once into a ws image in swizzled LDS-byte order,
// staged via linear global_load_lds, double-buffered with counted vmcnt.
// score = 2*dot - e^2  (x^2 dropped: per-row constant, argmax-invariant).
// dot_f32 ~= xh*eh + xh*el + xl*eh (3 MFMA passes, fp32 accumulate).

#define Cdim    128
#define KCODES  1024
#define CH      128       // codes per chunk
#define NCH     8
#define BROWS   256       // rows per block (4 waves x 64 rows)
#define THREADS 256
#define IMG_CHUNK_BYTES 65536   // [Bh 32KB | Bl 32KB]

typedef _Float16 f16;
typedef __attribute__((ext_vector_type(8)))  _Float16 f16x8;
typedef __attribute__((ext_vector_type(16))) float    f32x16;

// ---------------- e_sq pre-pass (exact fp32) ----------------
__global__ __launch_bounds__(256) void esq_kernel(const float* __restrict__ embed,
                                                  float* __restrict__ esq, int K) {
    int gid  = blockIdx.x * blockDim.x + threadIdx.x;
    int code = gid >> 6;
    int lane = threadIdx.x & 63;
    if (code >= K) return;
    float2 v = ((const float2*)(embed + (size_t)code * Cdim))[lane];
    float  s = fmaf(v.x, v.x, v.y * v.y);
    #pragma unroll
    for (int m = 32; m >= 1; m >>= 1) s += __shfl_xor(s, m, 64);
    if (lane == 0) esq[code] = s;
}

__device__ __forceinline__ void cvt8(float4 a, float4 b, f16x8& h, f16x8& lo) {
    float v[8] = {a.x, a.y, a.z, a.w, b.x, b.y, b.z, b.w};
    #pragma unroll
    for (int i = 0; i < 8; ++i) {
        f16 hh = (f16)v[i];
        h[i]  = hh;
        lo[i] = (f16)(v[i] - (float)hh);
    }
}

// ---------------- codebook -> f16 hi/lo ws image (swizzled LDS-byte order) ----
__global__ __launch_bounds__(256) void bconv_kernel(const float* __restrict__ embed,
                                                    char* __restrict__ img) {
    int t    = threadIdx.x;
    int code = blockIdx.x * 16 + (t >> 4);   // global code 0..1023
    int ks   = t & 15;                        // 8-elem k-segment 0..15
    const float4* p = (const float4*)(embed + (size_t)code * Cdim + ks * 8);
    float4 v0 = p[0], v1 = p[1];
    f16x8 h, lo;
    cvt8(v0, v1, h, lo);
    int ch = code >> 7, c = code & 127;
    size_t base = (size_t)ch * IMG_CHUNK_BYTES + (size_t)c * 256
                + ((ks * 16) ^ ((c & 7) << 4));
    *(f16x8*)(img + base)         = h;
    *(f16x8*)(img + base + 32768) = lo;
}

// ---------------- async global->LDS 16B ----------------
__device__ __forceinline__ void gll16(const void* g, void* l) {
    __builtin_amdgcn_global_load_lds(
        (const __attribute__((address_space(1))) unsigned int*)g,
        (__attribute__((address_space(3))) unsigned int*)l, 16, 0, 0);
}

__global__ __launch_bounds__(THREADS, 1) void vq32_kernel(
    const float* __restrict__ x, const float* __restrict__ embed,
    const float* __restrict__ esq, const char* __restrict__ img,
    float* __restrict__ outq, float* __restrict__ outi) {

    __shared__ __align__(16) char Bbuf[2][IMG_CHUNK_BYTES];   // 128KB
    __shared__ int winners[BROWS];

    const int tid  = threadIdx.x;
    const int wid  = tid >> 6;
    const int l    = tid & 63;
    const int lm   = l & 31;
    const int lh   = l >> 5;
    const int row0 = blockIdx.x * BROWS;
    const int wrow = row0 + wid * 64;

    // ---- issue chunk-0 staging first (hides under x load/convert) ----
    {
        const char* src = img + (size_t)wid * 16384 + (size_t)l * 16;
        char*       dst = &Bbuf[0][wid * 16384];           // wave-uniform base
        #pragma unroll
        for (int i = 0; i < 16; ++i) gll16(src + i * 1024, dst + i * 1024);
    }

    // ---- load x rows -> f16 hi/lo register fragments (coalesced 64B lines) ----
    f16x8 ah[2][8], al[2][8];
    #pragma unroll
    for (int m = 0; m < 2; ++m) {
        const float* xr = x + (size_t)(wrow + m * 32 + lm) * Cdim + lh * 8;
        #pragma unroll
        for (int kk = 0; kk < 8; ++kk) {
            float4 v0 = *(const float4*)(xr + kk * 16);
            float4 v1 = *(const float4*)(xr + kk * 16 + 4);
            cvt8(v0, v1, ah[m][kk], al[m][kk]);
        }
    }

    float best[2][16];
    int   bidx[2][16];
    #pragma unroll
    for (int m = 0; m < 2; ++m)
        #pragma unroll
        for (int r = 0; r < 16; ++r) { best[m][r] = -FLT_MAX; bidx[m][r] = 0; }

    #pragma unroll 1
    for (int ch = 0; ch < NCH; ++ch) {
        const int cur = ch & 1, nxt = cur ^ 1;

        __builtin_amdgcn_s_barrier();   // everyone done reading Bbuf[nxt] (chunk ch-1)

        if (ch + 1 < NCH) {             // prefetch chunk ch+1
            const char* src = img + (size_t)(ch + 1) * IMG_CHUNK_BYTES
                            + (size_t)wid * 16384 + (size_t)l * 16;
            char* dst = &Bbuf[nxt][wid * 16384];
            #pragma unroll
            for (int i = 0; i < 16; ++i) gll16(src + i * 1024, dst + i * 1024);
            asm volatile("s_waitcnt vmcnt(16)" ::: "memory");  // chunk ch staged (own)
        } else {
            asm volatile("s_waitcnt vmcnt(0)" ::: "memory");
        }
        __builtin_amdgcn_s_barrier();   // all waves' chunk-ch staging complete

        float eq[4];
        #pragma unroll
        for (int n = 0; n < 4; ++n) eq[n] = esq[ch * CH + n * 32 + lm];

        f32x16 acc[2][4];
        #pragma unroll
        for (int m = 0; m < 2; ++m)
            #pragma unroll
            for (int n = 0; n < 4; ++n)
                #pragma unroll
                for (int r = 0; r < 16; ++r) acc[m][n][r] = 0.f;

        #pragma unroll
        for (int kk = 0; kk < 8; ++kk) {
            f16x8 bh[4], bl[4];
            #pragma unroll
            for (int n = 0; n < 4; ++n) {
                const int off = (n * 32 + lm) * 256
                              + ((kk * 32 + lh * 16) ^ ((lm & 7) << 4));
                bh[n] = *(const f16x8*)(&Bbuf[cur][off]);
                bl[n] = *(const f16x8*)(&Bbuf[cur][off + 32768]);
            }
            #pragma unroll
            for (int m = 0; m < 2; ++m)
                #pragma unroll
                for (int n = 0; n < 4; ++n) {
                    acc[m][n] = __builtin_amdgcn_mfma_f32_32x32x16_f16(ah[m][kk], bh[n], acc[m][n], 0, 0, 0);
                    acc[m][n] = __builtin_amdgcn_mfma_f32_32x32x16_f16(ah[m][kk], bl[n], acc[m][n], 0, 0, 0);
                    acc[m][n] = __builtin_amdgcn_mfma_f32_32x32x16_f16(al[m][kk], bh[n], acc[m][n], 0, 0, 0);
                }
        }

        // fused scoring: s = 2*dot - e^2 ; first-max wins (codes ascend in ch,n)
        #pragma unroll
        for (int n = 0; n < 4; ++n) {
            const float ne   = -eq[n];
            const int   code = ch * CH + n * 32 + lm;
            #pragma unroll
            for (int m = 0; m < 2; ++m)
                #pragma unroll
                for (int r = 0; r < 16; ++r) {
                    float s = fmaf(2.f, acc[m][n][r], ne);
                    if (s > best[m][r]) { best[m][r] = s; bidx[m][r] = code; }
                }
        }
    }

    // ---- cross-lane argmax over the 32 code-lanes (ties -> lower index) ----
    #pragma unroll
    for (int m = 0; m < 2; ++m)
        #pragma unroll
        for (int r = 0; r < 16; ++r) {
            float bs = best[m][r]; int bi = bidx[m][r];
            #pragma unroll
            for (int msk = 1; msk <= 16; msk <<= 1) {
                float vs = __shfl_xor(bs, msk, 64);
                int   vi = __shfl_xor(bi, msk, 64);
                if (vs > bs || (vs == bs && vi < bi)) { bs = vs; bi = vi; }
            }
            if (lm == 0) {
                int rowloc = (r & 3) + 8 * (r >> 2) + 4 * lh;
                int grow   = wid * 64 + m * 32 + rowloc;
                winners[grow] = bi;
                outi[row0 + grow] = (float)bi;
            }
        }
    __syncthreads();

    // ---- gather quantized = embed[winner] (exact fp32 copy, coalesced) ----
    #pragma unroll
    for (int i = 0; i < 32; ++i) {
        int pos = i * 256 + tid;
        int r = pos >> 5, c4 = pos & 31;
        int idx = winners[r];
        float4 v = ((const float4*)(embed + (size_t)idx * Cdim))[c4];
        ((float4*)(outq + (size_t)(row0 + r) * Cdim))[c4] = v;
    }
}

extern "C" void kernel_launch(void* const* d_in, const int* in_sizes, int n_in,
                              void* d_out, int out_size, void* d_ws, size_t ws_size,
                              hipStream_t stream) {
    const float* x     = (const float*)d_in[0];
    const float* embed = (const float*)d_in[1];
    const int M = in_sizes[0] / Cdim;   // 65536
    const int K = in_sizes[1] / Cdim;   // 1024
    float* outq = (float*)d_out;
    float* outi = outq + (size_t)M * Cdim;
    float* esq  = (float*)d_ws;
    char*  img  = (char*)d_ws + 4096;   // 512KB f16 hi/lo codebook image

    esq_kernel <<<K / 4, 256, 0, stream>>>(embed, esq, K);
    bconv_kernel<<<K / 16, 256, 0, stream>>>(embed, img);
    vq32_kernel<<<M / BROWS, THREADS, 0, stream>>>(x, embed, esq, img, outq, outi);
}

// Round 4
// 75.954 us; speedup vs baseline: 6.2341x; 1.0554x over previous
//
#include <hip/hip_runtime.h>
#include <float.h>

// EuclideanCodebook R4: 32x32x16 f16-split MFMA (3 passes, 6 independent accs),
// A(x) in registers (32 rows/wave), B(codebook) pre-arranged in exact fragment
// order -> wave-linear conflict-free ds_read_b128 + linear global_load_lds.
// 512 blocks x 256 thr, 2 blocks/CU (LDS 69KB), dbuf CH=64, counted vmcnt(8).
// score = 2*dot - e^2 (x^2 dropped: per-row constant, argmax-invariant).

#define Cdim        128
#define KCODES      1024
#define CH          64        // codes per chunk
#define NCH         16
#define BROWS       128       // rows per block (4 waves x 32 rows)
#define THREADS     256
#define FRAG_OFF    4096      // ws layout: [esq 4KB | frag image 512KB]
#define CHUNK_BYTES 32768     // per chunk: hi 16KB + lo 16KB

typedef _Float16 f16;
typedef __attribute__((ext_vector_type(8)))  _Float16 f16x8;
typedef __attribute__((ext_vector_type(16))) float    f32x16;

// ---------------- e_sq pre-pass (exact fp32) ----------------
__global__ __launch_bounds__(256) void esq_kernel(const float* __restrict__ embed,
                                                  float* __restrict__ esq, int K) {
    int gid  = blockIdx.x * blockDim.x + threadIdx.x;
    int code = gid >> 6;
    int lane = threadIdx.x & 63;
    if (code >= K) return;
    float2 v = ((const float2*)(embed + (size_t)code * Cdim))[lane];
    float  s = fmaf(v.x, v.x, v.y * v.y);
    #pragma unroll
    for (int m = 32; m >= 1; m >>= 1) s += __shfl_xor(s, m, 64);
    if (lane == 0) esq[code] = s;
}

__device__ __forceinline__ void cvt8(float4 a, float4 b, f16x8& h, f16x8& lo) {
    float v[8] = {a.x, a.y, a.z, a.w, b.x, b.y, b.z, b.w};
    #pragma unroll
    for (int i = 0; i < 8; ++i) {
        f16 hh = (f16)v[i];
        h[i]  = hh;
        lo[i] = (f16)(v[i] - (float)hh);
    }
}

// ---- codebook -> f16 hi/lo image in EXACT fragment order ----
// lane (lh,lm) of a wave reading frag (n,kk) wants e[n*32+lm][kk*16+lh*8 .. +8]
// at chunk_base + ((n*8+kk)*2+lh)*512 + lm*16  (hi; lo at +16KB).
__global__ __launch_bounds__(256) void bconv_kernel(const float* __restrict__ embed,
                                                    char* __restrict__ img) {
    int t    = blockIdx.x * 256 + threadIdx.x;   // 16384 threads total
    int code = t >> 4;
    int seg  = t & 15;
    int kk   = seg >> 1;
    int lh   = seg & 1;
    const float4* p = (const float4*)(embed + (size_t)code * Cdim + kk * 16 + lh * 8);
    float4 v0 = p[0], v1 = p[1];
    f16x8 h, lo;
    cvt8(v0, v1, h, lo);
    int ch = code >> 6, n = (code >> 5) & 1, lm = code & 31;
    size_t base = FRAG_OFF + (size_t)ch * CHUNK_BYTES
                + (size_t)(((n * 8 + kk) * 2 + lh) * 512 + lm * 16);
    *(f16x8*)(img + base)         = h;
    *(f16x8*)(img + base + 16384) = lo;
}

// ---------------- async global->LDS 16B ----------------
__device__ __forceinline__ void gll16(const void* g, void* l) {
    __builtin_amdgcn_global_load_lds(
        (const __attribute__((address_space(1))) unsigned int*)g,
        (__attribute__((address_space(3))) unsigned int*)l, 16, 0, 0);
}

__global__ __launch_bounds__(THREADS, 2) void vq_kernel(
    const float* __restrict__ x, const float* __restrict__ embed,
    const char* __restrict__ ws, float* __restrict__ outq,
    float* __restrict__ outi) {

    __shared__ __align__(16) char  Bb[2][CHUNK_BYTES];   // 64KB dbuf
    __shared__ __align__(16) float esq_lds[KCODES];      // 4KB
    __shared__ int winners[BROWS];

    const int tid  = threadIdx.x;
    const int wid  = tid >> 6;
    const int l    = tid & 63;
    const int lm   = l & 31;
    const int lh   = l >> 5;
    const int row0 = blockIdx.x * BROWS;

    const char* frag = ws + FRAG_OFF;

    // ---- stage chunk 0 + esq (DMA; counted by vmcnt) ----
    {
        const char* src = frag + wid * 8192 + (size_t)l * 16;
        char*       dst = &Bb[0][wid * 8192];
        #pragma unroll
        for (int i = 0; i < 8; ++i) gll16(src + i * 1024, dst + i * 1024);
        gll16(ws + wid * 1024 + (size_t)l * 16, (char*)esq_lds + wid * 1024);
    }

    // ---- x rows -> f16 hi/lo register fragments ----
    f16x8 ah[8], al[8];
    {
        const float* xr = x + (size_t)(row0 + wid * 32 + lm) * Cdim + lh * 8;
        #pragma unroll
        for (int kk = 0; kk < 8; ++kk) {
            float4 v0 = *(const float4*)(xr + kk * 16);
            float4 v1 = *(const float4*)(xr + kk * 16 + 4);
            cvt8(v0, v1, ah[kk], al[kk]);
        }
    }

    float best[16]; int bidx[16];
    #pragma unroll
    for (int r = 0; r < 16; ++r) { best[r] = -FLT_MAX; bidx[r] = 0; }

    #pragma unroll 1
    for (int ch = 0; ch < NCH; ++ch) {
        const int cur = ch & 1, nxt = cur ^ 1;

        __builtin_amdgcn_s_barrier();           // safe to overwrite Bb[nxt]

        if (ch + 1 < NCH) {                     // prefetch chunk ch+1
            const char* src = frag + (size_t)(ch + 1) * CHUNK_BYTES
                            + wid * 8192 + (size_t)l * 16;
            char* dst = &Bb[nxt][wid * 8192];
            #pragma unroll
            for (int i = 0; i < 8; ++i) gll16(src + i * 1024, dst + i * 1024);
            asm volatile("s_waitcnt vmcnt(8)" ::: "memory");   // chunk ch done
        } else {
            asm volatile("s_waitcnt vmcnt(0)" ::: "memory");
        }
        __builtin_amdgcn_s_barrier();           // all waves staged chunk ch

        const float eq0 = esq_lds[ch * CH + lm];
        const float eq1 = esq_lds[ch * CH + 32 + lm];

        f32x16 a00, a01, a10, a11, a20, a21;
        #pragma unroll
        for (int r = 0; r < 16; ++r) {
            a00[r] = 0.f; a01[r] = 0.f; a10[r] = 0.f;
            a11[r] = 0.f; a20[r] = 0.f; a21[r] = 0.f;
        }

        const char* bb = &Bb[cur][(size_t)l * 16];
        #pragma unroll
        for (int kk = 0; kk < 8; ++kk) {
            f16x8 bh0 = *(const f16x8*)(bb + kk * 1024);
            f16x8 bh1 = *(const f16x8*)(bb + 8192  + kk * 1024);
            f16x8 bl0 = *(const f16x8*)(bb + 16384 + kk * 1024);
            f16x8 bl1 = *(const f16x8*)(bb + 24576 + kk * 1024);
            a00 = __builtin_amdgcn_mfma_f32_32x32x16_f16(ah[kk], bh0, a00, 0, 0, 0);
            a01 = __builtin_amdgcn_mfma_f32_32x32x16_f16(ah[kk], bh1, a01, 0, 0, 0);
            a10 = __builtin_amdgcn_mfma_f32_32x32x16_f16(ah[kk], bl0, a10, 0, 0, 0);
            a11 = __builtin_amdgcn_mfma_f32_32x32x16_f16(ah[kk], bl1, a11, 0, 0, 0);
            a20 = __builtin_amdgcn_mfma_f32_32x32x16_f16(al[kk], bh0, a20, 0, 0, 0);
            a21 = __builtin_amdgcn_mfma_f32_32x32x16_f16(al[kk], bh1, a21, 0, 0, 0);
        }

        // fused scoring: s = 2*dot - e^2 ; codes ascend (n=0 then n=1), strict >
        const int code0 = ch * CH + lm;
        #pragma unroll
        for (int r = 0; r < 16; ++r) {
            float s0 = fmaf(2.f, (a00[r] + a10[r]) + a20[r], -eq0);
            float s1 = fmaf(2.f, (a01[r] + a11[r]) + a21[r], -eq1);
            if (s0 > best[r]) { best[r] = s0; bidx[r] = code0; }
            if (s1 > best[r]) { best[r] = s1; bidx[r] = code0 + 32; }
        }
    }

    // ---- cross-lane argmax over 32 code-lanes (ties -> lower index) ----
    #pragma unroll
    for (int r = 0; r < 16; ++r) {
        float bs = best[r]; int bi = bidx[r];
        #pragma unroll
        for (int m = 1; m <= 16; m <<= 1) {
            float vs = __shfl_xor(bs, m, 64);
            int   vi = __shfl_xor(bi, m, 64);
            if (vs > bs || (vs == bs && vi < bi)) { bs = vs; bi = vi; }
        }
        if (lm == 0) {
            int grow = wid * 32 + (r & 3) + 8 * (r >> 2) + 4 * lh;
            winners[grow] = bi;
            outi[row0 + grow] = (float)bi;
        }
    }
    __syncthreads();

    // ---- gather quantized = embed[winner] (exact fp32 copy) ----
    #pragma unroll
    for (int i = 0; i < 16; ++i) {
        int pos = i * 256 + tid;
        int r = pos >> 5, c4 = pos & 31;
        int idx = winners[r];
        float4 v = ((const float4*)(embed + (size_t)idx * Cdim))[c4];
        ((float4*)(outq + (size_t)(row0 + r) * Cdim))[c4] = v;
    }
}

extern "C" void kernel_launch(void* const* d_in, const int* in_sizes, int n_in,
                              void* d_out, int out_size, void* d_ws, size_t ws_size,
                              hipStream_t stream) {
    const float* x     = (const float*)d_in[0];
    const float* embed = (const float*)d_in[1];
    const int M = in_sizes[0] / Cdim;   // 65536
    const int K = in_sizes[1] / Cdim;   // 1024
    float* outq = (float*)d_out;
    float* outi = outq + (size_t)M * Cdim;

    esq_kernel <<<K / 4, 256, 0, stream>>>(embed, (float*)d_ws, K);
    bconv_kernel<<<64,    256, 0, stream>>>(embed, (char*)d_ws);
    vq_kernel  <<<M / BROWS, THREADS, 0, stream>>>(x, embed, (const char*)d_ws,
                                                   outq, outi);
}